// Round 10
// baseline (459.377 us; speedup 1.0000x reference)
//
#include <hip/hip_runtime.h>

// N=2, S=2048, E=2048, H=16, Dk=128.  M=N*S=4096, K=E=2048.

typedef __attribute__((ext_vector_type(8))) short bf16x8;
typedef __attribute__((ext_vector_type(4))) short bf16x4;
typedef __attribute__((ext_vector_type(4))) float f32x4;
typedef __attribute__((ext_vector_type(16))) float f32x16;
typedef unsigned int u32;

__device__ __forceinline__ unsigned short f2bf(float f) {
    unsigned u = __float_as_uint(f);
    u += 0x7fffu + ((u >> 16) & 1u);   // RNE
    return (unsigned short)(u >> 16);
}

// truncation pack (P is non-negative; uniform downward bias cancels in O = sum(Pv)/sum(P))
__device__ __forceinline__ u32 pack2bf_t(float lo, float hi) {
    return (__float_as_uint(lo) >> 16) | (__float_as_uint(hi) & 0xffff0000u);
}

__device__ __forceinline__ void gload_lds16(const unsigned short* g, unsigned short* l) {
    __builtin_amdgcn_global_load_lds(
        (const __attribute__((address_space(1))) unsigned int*)g,
        (__attribute__((address_space(3))) unsigned int*)l, 16, 0, 0);
}

// ---------------------------------------------------------------------------
// fp32 -> bf16 convert, two tensors per launch (c1 may be 0)
// ---------------------------------------------------------------------------
__global__ void cvt2(const float* __restrict__ s0, unsigned short* __restrict__ d0, int c0,
                     const float* __restrict__ s1, unsigned short* __restrict__ d1, int c1)
{
    int total = c0 + c1;
    for (int i = blockIdx.x * blockDim.x + threadIdx.x; i < total; i += gridDim.x * blockDim.x) {
        const float* s; unsigned short* d; int j;
        if (i < c0) { s = s0; d = d0; j = i; } else { s = s1; d = d1; j = i - c0; }
        float4 a = ((const float4*)s)[j * 2];
        float4 b = ((const float4*)s)[j * 2 + 1];
        bf16x8 r;
        r[0] = (short)f2bf(a.x); r[1] = (short)f2bf(a.y);
        r[2] = (short)f2bf(a.z); r[3] = (short)f2bf(a.w);
        r[4] = (short)f2bf(b.x); r[5] = (short)f2bf(b.y);
        r[6] = (short)f2bf(b.z); r[7] = (short)f2bf(b.w);
        ((bf16x8*)d)[j] = r;
    }
}

// ---------------------------------------------------------------------------
// GEMM (unchanged, proven): C[m][j] = (sum_k A[m][k]*B[j][k] + bias[j]) * cscale
// ---------------------------------------------------------------------------
template<int MODE>
__global__ __launch_bounds__(256, 2) void gemm_bt2(
    const unsigned short* __restrict__ A, const unsigned short* __restrict__ B,
    const float* __restrict__ bias, void* __restrict__ Cout, float cscale)
{
    const int K = 2048;
    __shared__ __align__(16) unsigned short SM[32768];

    const int tid  = threadIdx.x;
    const int lane = tid & 63;
    const int w    = tid >> 6;
    const int wr   = w >> 1, wc = w & 1;

    int bid = blockIdx.x;
    int bl  = (bid & 7) * 64 + (bid >> 3);
    const int m0 = (bl & 31) << 7;
    const int n0 = (bl >> 5) << 7;

    const int lr8 = lane >> 3;
    const int sc8 = (lane & 7) ^ lr8;

    f32x4 acc[4][4];
    #pragma unroll
    for (int i = 0; i < 4; ++i)
        #pragma unroll
        for (int j = 0; j < 4; ++j) { f32x4 z = {0.f,0.f,0.f,0.f}; acc[i][j] = z; }

    auto stage = [&](int kt, unsigned short* As_, unsigned short* Bs_) {
        const int k0 = kt * 64;
        #pragma unroll
        for (int i = 0; i < 4; ++i) {
            int row = w * 32 + i * 8 + lr8;
            gload_lds16(A + (size_t)(m0 + row) * K + k0 + sc8 * 8, As_ + (w * 4 + i) * 512);
            gload_lds16(B + (size_t)(n0 + row) * K + k0 + sc8 * 8, Bs_ + (w * 4 + i) * 512);
        }
    };

    stage(0, SM, SM + 8192);
    __syncthreads();

    int cur = 0;
    for (int kt = 0; kt < 32; ++kt) {
        unsigned short* As_ = SM + (cur ? 16384 : 0);
        unsigned short* Bs_ = As_ + 8192;
        if (kt < 31) stage(kt + 1, SM + (cur ? 0 : 16384), SM + (cur ? 8192 : 24576));

        #pragma unroll
        for (int kk = 0; kk < 2; ++kk) {
            const int kc = kk * 32 + (lane >> 4) * 8;
            bf16x8 af[4], bfr[4];
            #pragma unroll
            for (int t = 0; t < 4; ++t) {
                int ar = wr * 64 + t * 16 + (lane & 15);
                af[t]  = *(const bf16x8*)&As_[ar * 64 + (kc ^ ((ar & 7) << 3))];
                int br = wc * 64 + t * 16 + (lane & 15);
                bfr[t] = *(const bf16x8*)&Bs_[br * 64 + (kc ^ ((br & 7) << 3))];
            }
            #pragma unroll
            for (int tm = 0; tm < 4; ++tm)
                #pragma unroll
                for (int tn = 0; tn < 4; ++tn)
                    acc[tm][tn] = __builtin_amdgcn_mfma_f32_16x16x32_bf16(
                        af[tm], bfr[tn], acc[tm][tn], 0, 0, 0);
        }
        __syncthreads();
        cur ^= 1;
    }

    const int lr = lane >> 4, lc = lane & 15;
    #pragma unroll
    for (int tn = 0; tn < 4; ++tn) {
        int col = n0 + wc * 64 + tn * 16 + lc;
        float bv = bias[col];
        #pragma unroll
        for (int tm = 0; tm < 4; ++tm) {
            int row0 = m0 + wr * 64 + tm * 16 + lr * 4;
            if constexpr (MODE == 1) {
                #pragma unroll
                for (int r = 0; r < 4; ++r)
                    ((float*)Cout)[(size_t)(row0 + r) * 2048 + col] = acc[tm][tn][r] + bv;
            } else if constexpr (MODE == 0) {
                #pragma unroll
                for (int r = 0; r < 4; ++r) {
                    int row = row0 + r;
                    int nb = row >> 11, s = row & 2047, h = col >> 7, d = col & 127;
                    ((unsigned short*)Cout)[(((size_t)(nb * 16 + h)) * 2048 + s) * 128 + d] =
                        f2bf((acc[tm][tn][r] + bv) * cscale);
                }
            } else {
                int nb = row0 >> 11, s0 = row0 & 2047, h = col >> 7, d = col & 127;
                bf16x4 pk;
                #pragma unroll
                for (int r = 0; r < 4; ++r) pk[r] = (short)f2bf(acc[tm][tn][r] + bv);
                *(bf16x4*)&((unsigned short*)Cout)[(((size_t)(nb * 16 + h)) * 128 + d) * 2048 + s0] = pk;
            }
        }
    }
}

// ---------------------------------------------------------------------------
// Flash attention v4: same per-warp math as v3 (verified), but QBLK=128 with
// 4 warps / 256 threads, grid 512 -> 2 independent blocks per CU.
// Phase diversity: block A's softmax VALU overlaps block B's MFMA (m114).
// Swapped QK^T (S^T = K Q^T), in-register softmax (log2 domain), truncation
// P-pack, PV as O^T = V^T P^T. Double-buffered global_load_lds K/V staging.
// ---------------------------------------------------------------------------
__global__ __launch_bounds__(256, 2) void attn_fwd4(
    const unsigned short* __restrict__ Qb, const unsigned short* __restrict__ Kb,
    const unsigned short* __restrict__ Vtb, unsigned short* __restrict__ Ob)
{
    __shared__ __align__(16) unsigned short SM[32768];  // 2 x (K 8192 | V 8192) shorts = 64 KB

    const int tid = threadIdx.x, lane = tid & 63, w = tid >> 6;
    const int l31 = lane & 31, h = lane >> 5;

    int bid = blockIdx.x;
    int bl  = (bid & 7) * 64 + (bid >> 3);   // 512 = 8*64 bijective; 4 heads/XCD
    const int qt = bl & 15;
    const int hb = bl >> 4;                  // 0..31

    const unsigned short* kgb = Kb  + (size_t)hb * 2048 * 128;
    const unsigned short* vgb = Vtb + (size_t)hb * 128 * 2048;

    auto stage = [&](int kt, int c) {
        unsigned short* Kl = SM + c * 16384;
        unsigned short* Vl = Kl + 8192;
        #pragma unroll
        for (int i = 0; i < 4; ++i) {
            int ck = tid + i * 256;          // 1024 chunks each for K and V
            int kr = ck >> 4, kc = (ck & 15) ^ (kr & 15);
            gload_lds16(kgb + (size_t)(kt * 64 + kr) * 128 + kc * 8, Kl + ck * 8);
            int vr = ck >> 3, vc = (ck & 7) ^ (vr & 7);
            gload_lds16(vgb + (size_t)vr * 2048 + kt * 64 + vc * 8, Vl + ck * 8);
        }
    };

    // Q fragments: q = lane&31 (B-operand col), d = ds*16 + 8h + e
    bf16x8 qf[8];
    const int qrow = qt * 128 + w * 32 + l31;
    {
        const unsigned short* qp = Qb + ((size_t)hb * 2048 + qrow) * 128 + h * 8;
        #pragma unroll
        for (int ds = 0; ds < 8; ++ds)
            qf[ds] = *(const bf16x8*)(qp + ds * 16);
    }

    stage(0, 0);

    f32x16 o[4];
    #pragma unroll
    for (int d = 0; d < 4; ++d)
        #pragma unroll
        for (int r = 0; r < 16; ++r) o[d][r] = 0.f;
    float m_ = -INFINITY, l_ = 0.f;

    __syncthreads();

    for (int kt = 0; kt < 32; ++kt) {
        int cur = kt & 1;
        if (kt < 31) stage(kt + 1, cur ^ 1);
        unsigned short* Kl = SM + cur * 16384;
        unsigned short* Vl = Kl + 8192;

        // QK^T: S^T[k][q], two 32-k blocks. A=K rows (row=l31), B=Q (col=l31).
        f32x16 sA, sB;
        #pragma unroll
        for (int r = 0; r < 16; ++r) { sA[r] = 0.f; sB[r] = 0.f; }
        __builtin_amdgcn_s_setprio(1);
        #pragma unroll
        for (int ds = 0; ds < 8; ++ds) {
            int ch = ds * 2 + h;
            int sw = (ch ^ (l31 & 15)) << 3;
            bf16x8 k0 = *(const bf16x8*)&Kl[l31 * 128 + sw];
            bf16x8 k1 = *(const bf16x8*)&Kl[(32 + l31) * 128 + sw];
            sA = __builtin_amdgcn_mfma_f32_32x32x16_bf16(k0, qf[ds], sA, 0, 0, 0);
            sB = __builtin_amdgcn_mfma_f32_32x32x16_bf16(k1, qf[ds], sB, 0, 0, 0);
        }
        __builtin_amdgcn_s_setprio(0);

        // row max (lane-local 32 values + one cross-half swap)
        float mx[16];
        #pragma unroll
        for (int r = 0; r < 16; ++r) mx[r] = fmaxf(sA[r], sB[r]);
        #pragma unroll
        for (int st = 8; st > 0; st >>= 1)
            #pragma unroll
            for (int r = 0; r < st; ++r) mx[r] = fmaxf(mx[r], mx[r + st]);
        float pmax = fmaxf(mx[0], __shfl_xor(mx[0], 32));

        // defer-max rescale (log2 domain; P <= 2^8)
        if (__any(pmax - m_ > 8.0f)) {
            float nm = fmaxf(m_, pmax);
            float sc = exp2f(m_ - nm);
            m_ = nm; l_ *= sc;
            #pragma unroll
            for (int d = 0; d < 4; ++d)
                #pragma unroll
                for (int r = 0; r < 16; ++r) o[d][r] *= sc;
        }

        // P = 2^(s - m)
        float p[32];
        float sm[16];
        #pragma unroll
        for (int r = 0; r < 16; ++r) {
            p[r]      = exp2f(sA[r] - m_);
            p[16 + r] = exp2f(sB[r] - m_);
            sm[r] = p[r] + p[16 + r];
        }
        #pragma unroll
        for (int st = 8; st > 0; st >>= 1)
            #pragma unroll
            for (int r = 0; r < st; ++r) sm[r] += sm[r + st];
        l_ += sm[0] + __shfl_xor(sm[0], 32);

        // pack P into PV operand fragments: pa[ks] covers k = ks*16 + 8h + e
        u32 paw[4][4];
        #pragma unroll
        for (int kb = 0; kb < 2; ++kb) {
            #pragma unroll
            for (int sg = 0; sg < 2; ++sg) {
                const int b = kb * 16 + 8 * sg;
                u32 w0 = pack2bf_t(p[b + 0], p[b + 1]);
                u32 w1 = pack2bf_t(p[b + 2], p[b + 3]);
                u32 w2 = pack2bf_t(p[b + 4], p[b + 5]);
                u32 w3 = pack2bf_t(p[b + 6], p[b + 7]);
                u32 s0 = h ? w0 : w2, s1 = h ? w1 : w3;
                u32 r0 = __shfl_xor(s0, 32), r1 = __shfl_xor(s1, 32);
                int ks = kb * 2 + sg;
                paw[ks][0] = h ? r0 : w0;
                paw[ks][1] = h ? r1 : w1;
                paw[ks][2] = h ? w2 : r0;
                paw[ks][3] = h ? w3 : r1;
            }
        }

        // PV: O^T[d][q] += V^T[d][k] P^T[k][q]; A=V^T rows (row=l31), B=pa (col=l31)
        __builtin_amdgcn_s_setprio(1);
        #pragma unroll
        for (int ks = 0; ks < 4; ++ks) {
            union { u32 u[4]; bf16x8 v; } pu;
            pu.u[0] = paw[ks][0]; pu.u[1] = paw[ks][1];
            pu.u[2] = paw[ks][2]; pu.u[3] = paw[ks][3];
            bf16x8 pa = pu.v;
            int ch = ks * 2 + h;
            #pragma unroll
            for (int db = 0; db < 4; ++db) {
                int vr = db * 32 + l31;
                bf16x8 vf = *(const bf16x8*)&Vl[vr * 64 + ((ch ^ (vr & 7)) << 3)];
                o[db] = __builtin_amdgcn_mfma_f32_32x32x16_bf16(vf, pa, o[db], 0, 0, 0);
            }
        }
        __builtin_amdgcn_s_setprio(0);

        __syncthreads();
    }

    // epilogue: lane holds O^T: q = l31, d = db*32 + (reg&3) + 8*(reg>>2) + 4h
    float inv = 1.0f / l_;
    unsigned short* op = Ob + ((size_t)hb * 2048 + qrow) * 128;
    #pragma unroll
    for (int db = 0; db < 4; ++db) {
        #pragma unroll
        for (int g = 0; g < 4; ++g) {
            bf16x4 pk;
            #pragma unroll
            for (int j = 0; j < 4; ++j) pk[j] = (short)f2bf(o[db][g * 4 + j] * inv);
            *(bf16x4*)&op[db * 32 + 8 * g + 4 * h] = pk;
        }
    }
}

extern "C" void kernel_launch(void* const* d_in, const int* in_sizes, int n_in,
                              void* d_out, int out_size, void* d_ws, size_t ws_size,
                              hipStream_t stream) {
    const float* query = (const float*)d_in[0];
    const float* key   = (const float*)d_in[1];
    const float* value = (const float*)d_in[2];
    const float* Wq    = (const float*)d_in[3];
    const float* bq    = (const float*)d_in[4];
    const float* Wk    = (const float*)d_in[5];
    const float* bk    = (const float*)d_in[6];
    const float* Wv    = (const float*)d_in[7];
    const float* bv    = (const float*)d_in[8];
    const float* Wo    = (const float*)d_in[9];
    const float* bo    = (const float*)d_in[10];

    unsigned short* Qb  = (unsigned short*)d_ws;
    unsigned short* Kb  = Qb  + 8388608;
    unsigned short* Vtb = Kb  + 8388608;
    unsigned short* Xs  = Vtb + 8388608;
    unsigned short* Wsl = (unsigned short*)d_out;
    unsigned short* Wos = Qb;

    const int CX = 1048576;
    const int CW = 524288;
    // 1/sqrt(128) * log2(e): attention softmax runs in log2 domain (exp2f)
    const float qscale = 0.08838834764831845f * 1.4426950408889634f;

    dim3 B(256);
    cvt2<<<dim3(1024), B, 0, stream>>>(value, Xs, CX, Wv, Wsl, CW);
    gemm_bt2<2><<<dim3(512), B, 0, stream>>>(Xs, Wsl, bv, Vtb, 1.0f);
    cvt2<<<dim3(1024), B, 0, stream>>>(query, Xs, CX, Wq, Wsl, CW);
    gemm_bt2<0><<<dim3(512), B, 0, stream>>>(Xs, Wsl, bq, Qb, qscale);
    cvt2<<<dim3(1024), B, 0, stream>>>(key, Xs, CX, Wk, Wsl, CW);
    gemm_bt2<0><<<dim3(512), B, 0, stream>>>(Xs, Wsl, bk, Kb, 1.0f);
    attn_fwd4<<<dim3(512), dim3(256), 0, stream>>>(Qb, Kb, Vtb, Xs);
    cvt2<<<dim3(512), B, 0, stream>>>(Wo, Wos, CW, Wo, Wos, 0);
    gemm_bt2<1><<<dim3(512), B, 0, stream>>>(Xs, Wos, bo, d_out, 1.0f);
}